// Round 21
// baseline (804.078 us; speedup 1.0000x reference)
//
#include <hip/hip_runtime.h>
#include <math.h>

#define NB 16
#define NS 4096
#define ND 1024
#define NH 16
#define LUTN 4096
#define NC 32            // s-chunks (grid = NB*NC = 512 blocks, 2/CU)
#define SC (NS / NC)     // 128 rows per block
#define RG 16            // rows per group
#define NG (SC / RG)     // 8 groups

#define KF   651.8986469044033f      // LUT_SIZE / (2*pi)
#define PHIF 1.6180339887498949f
#define REVF 2.44140625e-4f          // 1/4096 (exact) — LUT step in revolutions
#define INV2PI 0.15915494309189535f  // 1/(2*pi): radians -> revolutions
#define EXPC 0.1275174394255169f     // log2(e) / sqrt(2*dh)

// workspace layout, in floats
#define OFF_P     0          // P[NC][NB][NH][ND] f32 = 8388608 floats (33.5 MB)
#define OFF_ZPART 8388608    // [NC][NB][NH] = 8192
#define OFF_INVZ  8396800    // [NB*NH] = 256
#define OFF_PROBE 33554432   // probe scratch (128 MB offset; ws ~1 GiB)

// 16-lane-group sum via DPP row_shr (pure VALU); lane 16k+15 holds the sum.
__device__ __forceinline__ float dpp_reduce16(float p) {
    int y;
    y = __builtin_amdgcn_update_dpp(0, __float_as_int(p), 0x111, 0xF, 0xF, true);
    p += __int_as_float(y);
    y = __builtin_amdgcn_update_dpp(0, __float_as_int(p), 0x112, 0xF, 0xF, true);
    p += __int_as_float(y);
    y = __builtin_amdgcn_update_dpp(0, __float_as_int(p), 0x114, 0xF, 0xF, true);
    p += __int_as_float(y);
    y = __builtin_amdgcn_update_dpp(0, __float_as_int(p), 0x118, 0xF, 0xF, true);
    p += __int_as_float(y);
    return p;
}

#if __has_builtin(__builtin_amdgcn_exp2f)
#define EXP2F(x) __builtin_amdgcn_exp2f(x)
#else
#define EXP2F(x) exp2f(x)
#endif

// Packed FP32 FMA (VOP3P). src1 low/high half broadcast via op_sel.
#define PKFMA_LO(acc, e2, v2) \
    asm("v_pk_fma_f32 %0, %1, %2, %0 op_sel:[0,0,0] op_sel_hi:[1,0,1]" \
        : "+v"(acc) : "v"(e2), "v"(v2))
#define PKFMA_HI(acc, e2, v2) \
    asm("v_pk_fma_f32 %0, %1, %2, %0 op_sel:[0,1,0] op_sel_hi:[1,1,1]" \
        : "+v"(acc) : "v"(e2), "v"(v2))

// VAR: 0 = real full kernel; 2 = loads+score (no ACC); 11 = loads+score with
// group base PINNED (L2-hot reread — removes DRAM latency, keeps identical
// instruction structure); 4 = score-only (opaque synthetic v, no loads).
template<int VAR, int REP>
__device__ __forceinline__ void fused_body(const float* __restrict__ cached,
                                           const float* __restrict__ x,
                                           const float* __restrict__ t,
                                           const float* __restrict__ wq,
                                           const float* __restrict__ bq,
                                           const float* __restrict__ wk,
                                           const float* __restrict__ bk,
                                           float* __restrict__ Pout,
                                           float* __restrict__ Zout) {
    __shared__ float se[2][RG][16];
    int tid = threadIdx.x;
    int b = blockIdx.x >> 5;
    int c = blockIdx.x & (NC - 1);
    int s0 = c * SC;
    int m = tid * 4;

    float4 wkv = *(const float4*)(wk + m);
    float4 kbv = *(const float4*)(bk + m);
    float4 krR;
    krR.x = INV2PI / (1.0f + fabsf(wkv.x));
    krR.y = INV2PI / (1.0f + fabsf(wkv.y));
    krR.z = INV2PI / (1.0f + fabsf(wkv.z));
    krR.w = INV2PI / (1.0f + fabsf(wkv.w));

    float tphi = t[b] * PHIF;
    float4 xv = *(const float4*)(x + b * ND + m);
    float4 wqv = *(const float4*)(wq + m);
    float4 bqv = *(const float4*)(bq + m);
    float4 kdR;
    kdR.x = kbv.x * INV2PI - rintf((xv.x / (1.0f + fabsf(wqv.x)) + bqv.x + tphi) * KF) * REVF;
    kdR.y = kbv.y * INV2PI - rintf((xv.y / (1.0f + fabsf(wqv.y)) + bqv.y + tphi) * KF) * REVF;
    kdR.z = kbv.z * INV2PI - rintf((xv.z / (1.0f + fabsf(wqv.z)) + bqv.z + tphi) * KF) * REVF;
    kdR.w = kbv.w * INV2PI - rintf((xv.w / (1.0f + fabsf(wqv.w)) + bqv.w + tphi) * KF) * REVF;

    float2 acc2[8][4];
    float zacc = 0.f;
    const float* base = cached + ((size_t)b * NS + s0) * ND + m;
    float4 v[RG];

    // opaque seed for V4 (prevents CSE/LICM of the synthetic score chains)
    float opq;
    asm("v_mov_b32 %0, %1" : "=v"(opq) : "v"(krR.x));

    for (int rep = 0; rep < REP; ++rep) {
        #pragma unroll
        for (int p = 0; p < 8; ++p)
            #pragma unroll
            for (int q = 0; q < 4; ++q) acc2[p][q] = make_float2(0.f, 0.f);
        zacc = 0.f;

        for (int g = 0; g < NG; ++g) {
            if constexpr (VAR != 4) {
                const float* bp = (VAR == 11) ? base               // pinned: L2-hot
                                              : base + (size_t)g * (RG * ND);
                #pragma unroll
                for (int r = 0; r < RG; ++r)
                    v[r] = *(const float4*)(bp + (size_t)r * ND);
            } else {
                float gf = (float)g * 0.001f;
                #pragma unroll
                for (int r = 0; r < RG; ++r)
                    v[r] = make_float4(opq + (float)r + gf, opq * (float)(r + 1) + gf,
                                       opq - (float)r + gf, opq * 0.5f + (float)r + gf);
            }

            // score: one fma + one v_cos per element (v_cos takes revolutions)
            #pragma unroll
            for (int r = 0; r < RG; ++r) {
                float c0 = __builtin_amdgcn_cosf(fmaf(v[r].x, krR.x, kdR.x));
                float c1 = __builtin_amdgcn_cosf(fmaf(v[r].y, krR.y, kdR.y));
                float c2 = __builtin_amdgcn_cosf(fmaf(v[r].z, krR.z, kdR.z));
                float c3 = __builtin_amdgcn_cosf(fmaf(v[r].w, krR.w, kdR.w));
                float p = (c0 + c1) + (c2 + c3);
                p = dpp_reduce16(p);
                float e = EXP2F(p * EXPC);
                zacc += e;
                if ((tid & 15) == 15) se[g & 1][r][tid >> 4] = e;
            }
            __syncthreads();
            if constexpr (VAR == 0) {
                #pragma unroll
                for (int r = 0; r < RG; ++r) {
                    const float2* s2 = (const float2*)se[g & 1][r];
                    float2 vxy = make_float2(v[r].x, v[r].y);
                    float2 vzw = make_float2(v[r].z, v[r].w);
                    #pragma unroll
                    for (int p = 0; p < 8; ++p) {
                        float2 e2 = s2[p];
                        PKFMA_LO(acc2[p][0], e2, vxy);
                        PKFMA_HI(acc2[p][1], e2, vxy);
                        PKFMA_LO(acc2[p][2], e2, vzw);
                        PKFMA_HI(acc2[p][3], e2, vzw);
                    }
                }
            } else {
                float2 ka = *(const float2*)se[g & 1][0];
                asm volatile("" :: "v"(ka.x), "v"(ka.y));
            }
        }
    }

    float* P = Pout + (size_t)(c * NB + b) * (NH * ND) + m;
    #pragma unroll
    for (int p = 0; p < 8; ++p) {
        float4 lo = make_float4(acc2[p][0].x, acc2[p][1].x, acc2[p][2].x, acc2[p][3].x);
        float4 hi = make_float4(acc2[p][0].y, acc2[p][1].y, acc2[p][2].y, acc2[p][3].y);
        *(float4*)(P + (2 * p) * ND) = lo;
        *(float4*)(P + (2 * p + 1) * ND) = hi;
    }
    if ((tid & 15) == 15)
        Zout[(c * NB + b) * NH + (tid >> 4)] = zacc;
}

__global__ __launch_bounds__(256) void k_fused(const float* __restrict__ cached,
                                               const float* __restrict__ x,
                                               const float* __restrict__ t,
                                               const float* __restrict__ wq,
                                               const float* __restrict__ bq,
                                               const float* __restrict__ wk,
                                               const float* __restrict__ bk,
                                               float* __restrict__ ws) {
    fused_body<0, 1>(cached, x, t, wq, bq, wk, bk, ws + OFF_P, ws + OFF_ZPART);
}

template<int VAR, int REP>
__global__ __launch_bounds__(256) void k_probe(const float* __restrict__ cached,
                                               const float* __restrict__ x,
                                               const float* __restrict__ t,
                                               const float* __restrict__ wq,
                                               const float* __restrict__ bq,
                                               const float* __restrict__ wk,
                                               const float* __restrict__ bk,
                                               float* __restrict__ ws) {
    fused_body<VAR, REP>(cached, x, t, wq, bq, wk, bk,
                         ws + OFF_PROBE, ws + OFF_PROBE + 8388608);
}

__global__ __launch_bounds__(256) void k_z(float* __restrict__ ws) {
    int i = threadIdx.x;
    float s = 0.f;
    #pragma unroll
    for (int c = 0; c < NC; ++c) s += ws[OFF_ZPART + c * 256 + i];
    ws[OFF_INVZ + i] = 1.0f / s;
}

__global__ __launch_bounds__(256) void k_out(const float* __restrict__ t,
                                             const float* __restrict__ wo,
                                             const float* __restrict__ bo,
                                             const float* __restrict__ osc,
                                             const float* __restrict__ ws,
                                             float* __restrict__ out) {
    __shared__ float red[4][64];
    int bid = blockIdx.x;
    int b = bid >> 4, mc = bid & 15;
    int tid = threadIdx.x;
    int cq = tid >> 6, ml = tid & 63;
    int m = mc * 64 + ml;
    const float* P = ws + OFF_P;
    float ctx = 0.f;
    #pragma unroll
    for (int h = 0; h < NH; ++h) {
        float s = 0.f;
        #pragma unroll
        for (int i = 0; i < NC / 4; ++i) {
            int c = cq * (NC / 4) + i;
            s += P[(size_t)(c * NB + b) * (NH * ND) + h * ND + m];
        }
        ctx = fmaf(s, ws[OFF_INVZ + b * NH + h], ctx);
    }
    red[cq][ml] = ctx;
    __syncthreads();
    if (cq == 0) {
        ctx = ((red[0][ml] + red[1][ml]) + (red[2][ml] + red[3][ml]));
        float theta = ctx / (1.0f + fabsf(wo[m])) + bo[m] + t[b] * PHIF;
        int idx = ((int)rintf(theta * KF)) & (LUTN - 1);
        float ang = (float)idx * (2.0f * 3.14159265358979323846f / LUTN);
        out[b * ND + m] = osc[m] * (cosf(ang) + sinf(ang));
    }
}

extern "C" void kernel_launch(void* const* d_in, const int* in_sizes, int n_in,
                              void* d_out, int out_size, void* d_ws, size_t ws_size,
                              hipStream_t stream) {
    const float* x      = (const float*)d_in[0];
    const float* cached = (const float*)d_in[1];
    const float* t      = (const float*)d_in[2];
    const float* wq     = (const float*)d_in[3];
    const float* bq     = (const float*)d_in[4];
    const float* wk     = (const float*)d_in[5];
    const float* bk     = (const float*)d_in[6];
    const float* wo     = (const float*)d_in[7];
    const float* bo     = (const float*)d_in[8];
    const float* osc    = (const float*)d_in[9];
    float* ws  = (float*)d_ws;
    float* out = (float*)d_out;

    // ---- probes (scratch only): V2 anchor, V11 latency-removed, V4 no-loads
    k_probe<2, 8><<<NB * NC, 256, 0, stream>>>(cached, x, t, wq, bq, wk, bk, ws);
    k_probe<11, 8><<<NB * NC, 256, 0, stream>>>(cached, x, t, wq, bq, wk, bk, ws);
    k_probe<4, 24><<<NB * NC, 256, 0, stream>>>(cached, x, t, wq, bq, wk, bk, ws);

    // ---- real pipeline (R18-exact) ----
    k_fused<<<NB * NC, 256, 0, stream>>>(cached, x, t, wq, bq, wk, bk, ws);
    k_z<<<1, 256, 0, stream>>>(ws);
    k_out<<<NB * (ND / 64), 256, 0, stream>>>(t, wo, bo, osc, ws, out);
}

// Round 22
// 96.650 us; speedup vs baseline: 8.3195x; 8.3195x over previous
//
#include <hip/hip_runtime.h>
#include <math.h>

#define NB 16
#define NS 4096
#define ND 1024
#define NH 16
#define LUTN 4096
#define NC 32            // s-chunks (grid = NB*NC = 512 blocks, 2/CU)
#define SC (NS / NC)     // 128 rows per block
#define RG 8             // rows per period (vbuf 2x32KB -> 2 blocks/CU holds)
#define NG (SC / RG)     // 16 periods

#define KF   651.8986469044033f      // LUT_SIZE / (2*pi)
#define PHIF 1.6180339887498949f
#define REVF 2.44140625e-4f          // 1/4096 (exact) — LUT step in revolutions
#define INV2PI 0.15915494309189535f  // 1/(2*pi): radians -> revolutions
#define EXPC 0.1275174394255169f     // log2(e) / sqrt(2*dh)

// workspace layout, in floats
#define OFF_P     0          // P[NC][NB][NH][ND] f32 = 8388608 floats (33.5 MB)
#define OFF_ZPART 8388608    // [NC][NB][NH] = 8192
#define OFF_INVZ  8396800    // [NB*NH] = 256

// 16-lane-group sum via DPP row_shr (pure VALU); lane 16k+15 holds the sum.
__device__ __forceinline__ float dpp_reduce16(float p) {
    int y;
    y = __builtin_amdgcn_update_dpp(0, __float_as_int(p), 0x111, 0xF, 0xF, true);
    p += __int_as_float(y);
    y = __builtin_amdgcn_update_dpp(0, __float_as_int(p), 0x112, 0xF, 0xF, true);
    p += __int_as_float(y);
    y = __builtin_amdgcn_update_dpp(0, __float_as_int(p), 0x114, 0xF, 0xF, true);
    p += __int_as_float(y);
    y = __builtin_amdgcn_update_dpp(0, __float_as_int(p), 0x118, 0xF, 0xF, true);
    p += __int_as_float(y);
    return p;
}

#if __has_builtin(__builtin_amdgcn_exp2f)
#define EXP2F(x) __builtin_amdgcn_exp2f(x)
#else
#define EXP2F(x) exp2f(x)
#endif

// Packed FP32 FMA (VOP3P). src1 low/high half broadcast via op_sel.
#define PKFMA_LO(acc, e2, v2) \
    asm("v_pk_fma_f32 %0, %1, %2, %0 op_sel:[0,0,0] op_sel_hi:[1,0,1]" \
        : "+v"(acc) : "v"(e2), "v"(v2))
#define PKFMA_HI(acc, e2, v2) \
    asm("v_pk_fma_f32 %0, %1, %2, %0 op_sel:[0,1,0] op_sel_hi:[1,1,1]" \
        : "+v"(acc) : "v"(e2), "v"(v2))

// Fused scores + unnormalized per-head context, one pass over cached.
// R22: deferred-ACC pipeline. R21's decomposition: loads+score (V2) is near
// the 38 us floor, score alone (V4) is 15.5 us VALU-bound, ACC alone ~8 us —
// but the full kernel pays +34 us because v[16] (64 VGPR) must stay live
// across score->barrier->ACC, which at the ~108-reg allocation serializes
// the next group's loads behind ACC. Fix: v's register life ends at score
// (thread ds_writes its v to LDS); ACC(g-1) runs from LDS at the START of
// period g, right after loads(g) issue — it is the latency-hiding window.
// No load crosses a barrier (no vmcnt-drain interaction).
__global__ __launch_bounds__(256) void k_fused(const float* __restrict__ cached,
                                               const float* __restrict__ x,
                                               const float* __restrict__ t,
                                               const float* __restrict__ wq,
                                               const float* __restrict__ bq,
                                               const float* __restrict__ wk,
                                               const float* __restrict__ bk,
                                               float* __restrict__ ws) {
    __shared__ float vbuf[2][RG][ND];  // 2 x 32 KB row-group stash
    __shared__ float se[2][RG][16];    // e broadcast (1 KB)
    int tid = threadIdx.x;
    int b = blockIdx.x >> 5;           // / NC
    int c = blockIdx.x & (NC - 1);
    int s0 = c * SC;
    int m = tid * 4;

    // per-column constants: arg_rev = v * krR + kdR  (revolutions)
    float4 wkv = *(const float4*)(wk + m);
    float4 kbv = *(const float4*)(bk + m);
    float4 krR;
    krR.x = INV2PI / (1.0f + fabsf(wkv.x));
    krR.y = INV2PI / (1.0f + fabsf(wkv.y));
    krR.z = INV2PI / (1.0f + fabsf(wkv.z));
    krR.w = INV2PI / (1.0f + fabsf(wkv.w));

    float tphi = t[b] * PHIF;
    float4 xv = *(const float4*)(x + b * ND + m);
    float4 wqv = *(const float4*)(wq + m);
    float4 bqv = *(const float4*)(bq + m);
    float4 kdR;   // bk/(2pi) - rint(theta_q*KF)*REVF  (query stays quantized)
    kdR.x = kbv.x * INV2PI - rintf((xv.x / (1.0f + fabsf(wqv.x)) + bqv.x + tphi) * KF) * REVF;
    kdR.y = kbv.y * INV2PI - rintf((xv.y / (1.0f + fabsf(wqv.y)) + bqv.y + tphi) * KF) * REVF;
    kdR.z = kbv.z * INV2PI - rintf((xv.z / (1.0f + fabsf(wqv.z)) + bqv.z + tphi) * KF) * REVF;
    kdR.w = kbv.w * INV2PI - rintf((xv.w / (1.0f + fabsf(wqv.w)) + bqv.w + tphi) * KF) * REVF;

    // acc2[p][q] = (ctxh[2p][col q], ctxh[2p+1][col q]) — 64 VGPRs
    float2 acc2[8][4];
    #pragma unroll
    for (int p = 0; p < 8; ++p)
        #pragma unroll
        for (int q = 0; q < 4; ++q) acc2[p][q] = make_float2(0.f, 0.f);
    float zacc = 0.f;

    const float* base = cached + ((size_t)b * NS + s0) * ND + m;
    float4 v[RG];

#define LOADG(g) { \
    const float* bp = base + (size_t)(g) * (RG * ND); \
    _Pragma("unroll") \
    for (int r = 0; r < RG; ++r) v[r] = *(const float4*)(bp + (size_t)r * ND); }

    // score from regs; stash v and e into LDS (v's register life ends here)
#define SCOREW(g) { int gb = (g) & 1; \
    _Pragma("unroll") \
    for (int r = 0; r < RG; ++r) { \
        float c0 = __builtin_amdgcn_cosf(fmaf(v[r].x, krR.x, kdR.x)); \
        float c1 = __builtin_amdgcn_cosf(fmaf(v[r].y, krR.y, kdR.y)); \
        float c2 = __builtin_amdgcn_cosf(fmaf(v[r].z, krR.z, kdR.z)); \
        float c3 = __builtin_amdgcn_cosf(fmaf(v[r].w, krR.w, kdR.w)); \
        float p = (c0 + c1) + (c2 + c3); \
        p = dpp_reduce16(p); \
        float e = EXP2F(p * EXPC);   /* |score| <= 5.66, no max pass */ \
        zacc += e;                   /* valid in lanes 15 mod 16 */ \
        if ((tid & 15) == 15) se[gb][r][tid >> 4] = e; \
        *(float4*)(&vbuf[gb][r][m]) = v[r];   /* ds_write_b128, own slot */ \
    } }

    // ACC from LDS: re-read own v (1 ds_read_b128/row) + e broadcasts
#define ACCG(g) { int gb = (g) & 1; \
    _Pragma("unroll") \
    for (int r = 0; r < RG; ++r) { \
        float4 vv4 = *(const float4*)(&vbuf[gb][r][m]); \
        const float2* s2 = (const float2*)se[gb][r]; \
        float2 vxy = make_float2(vv4.x, vv4.y); \
        float2 vzw = make_float2(vv4.z, vv4.w); \
        _Pragma("unroll") \
        for (int p = 0; p < 8; ++p) { \
            float2 e2 = s2[p]; \
            PKFMA_LO(acc2[p][0], e2, vxy); \
            PKFMA_HI(acc2[p][1], e2, vxy); \
            PKFMA_LO(acc2[p][2], e2, vzw); \
            PKFMA_HI(acc2[p][3], e2, vzw); \
        } \
    } }

    LOADG(0)
    SCOREW(0)
    for (int g = 1; g < NG; ++g) {
        __syncthreads();    // se(g-1)/vbuf(g-1) visible; parity g&1 free (its
                            // readers ran in period g-1, before this barrier)
        LOADG(g)            // issue first: ACC(g-1) below is the hiding window
        ACCG(g - 1)
        SCOREW(g)           // consumes v regs; stashes them; regs die here
    }
    __syncthreads();
    ACCG(NG - 1)
#undef ACCG
#undef SCOREW
#undef LOADG

    // write per-head context partials, coalesced per h
    float* P = ws + OFF_P + (size_t)(c * NB + b) * (NH * ND) + m;
    #pragma unroll
    for (int p = 0; p < 8; ++p) {
        float4 lo = make_float4(acc2[p][0].x, acc2[p][1].x, acc2[p][2].x, acc2[p][3].x);
        float4 hi = make_float4(acc2[p][0].y, acc2[p][1].y, acc2[p][2].y, acc2[p][3].y);
        *(float4*)(P + (2 * p) * ND) = lo;
        *(float4*)(P + (2 * p + 1) * ND) = hi;
    }
    if ((tid & 15) == 15)
        ws[OFF_ZPART + (c * NB + b) * NH + (tid >> 4)] = zacc;
}

__global__ __launch_bounds__(256) void k_z(float* __restrict__ ws) {
    int i = threadIdx.x;   // b*NH + h
    float s = 0.f;
    #pragma unroll
    for (int c = 0; c < NC; ++c) s += ws[OFF_ZPART + c * 256 + i];
    ws[OFF_INVZ + i] = 1.0f / s;
}

__global__ __launch_bounds__(256) void k_out(const float* __restrict__ t,
                                             const float* __restrict__ wo,
                                             const float* __restrict__ bo,
                                             const float* __restrict__ osc,
                                             const float* __restrict__ ws,
                                             float* __restrict__ out) {
    __shared__ float red[4][64];
    int bid = blockIdx.x;          // NB*16 = 256
    int b = bid >> 4, mc = bid & 15;
    int tid = threadIdx.x;
    int cq = tid >> 6, ml = tid & 63;
    int m = mc * 64 + ml;
    const float* P = ws + OFF_P;
    float ctx = 0.f;
    #pragma unroll
    for (int h = 0; h < NH; ++h) {
        float s = 0.f;
        #pragma unroll
        for (int i = 0; i < NC / 4; ++i) {
            int c = cq * (NC / 4) + i;
            s += P[(size_t)(c * NB + b) * (NH * ND) + h * ND + m];
        }
        ctx = fmaf(s, ws[OFF_INVZ + b * NH + h], ctx);
    }
    red[cq][ml] = ctx;
    __syncthreads();
    if (cq == 0) {
        ctx = ((red[0][ml] + red[1][ml]) + (red[2][ml] + red[3][ml]));
        float theta = ctx / (1.0f + fabsf(wo[m])) + bo[m] + t[b] * PHIF;
        int idx = ((int)rintf(theta * KF)) & (LUTN - 1);
        float ang = (float)idx * (2.0f * 3.14159265358979323846f / LUTN);
        // precise libm trig: bit-matches the np table entries
        out[b * ND + m] = osc[m] * (cosf(ang) + sinf(ang));
    }
}

extern "C" void kernel_launch(void* const* d_in, const int* in_sizes, int n_in,
                              void* d_out, int out_size, void* d_ws, size_t ws_size,
                              hipStream_t stream) {
    const float* x      = (const float*)d_in[0];
    const float* cached = (const float*)d_in[1];
    const float* t      = (const float*)d_in[2];
    const float* wq     = (const float*)d_in[3];
    const float* bq     = (const float*)d_in[4];
    const float* wk     = (const float*)d_in[5];
    const float* bk     = (const float*)d_in[6];
    const float* wo     = (const float*)d_in[7];
    const float* bo     = (const float*)d_in[8];
    const float* osc    = (const float*)d_in[9];
    float* ws  = (float*)d_ws;
    float* out = (float*)d_out;

    k_fused<<<NB * NC, 256, 0, stream>>>(cached, x, t, wq, bq, wk, bk, ws);
    k_z<<<1, 256, 0, stream>>>(ws);
    k_out<<<NB * (ND / 64), 256, 0, stream>>>(t, wo, bo, osc, ws, out);
}

// Round 23
// 88.043 us; speedup vs baseline: 9.1328x; 1.0978x over previous
//
#include <hip/hip_runtime.h>
#include <math.h>

#define NB 16
#define NS 4096
#define ND 1024
#define NH 16
#define LUTN 4096
#define NC 32            // s-chunks (grid = NB*NC = 512 blocks, 2/CU)
#define SC (NS / NC)     // 128 rows per block
#define RG 8             // rows per buffer (vA/vB ping-pong)
#define NG (SC / RG)     // 16 groups

#define KF   651.8986469044033f      // LUT_SIZE / (2*pi)
#define PHIF 1.6180339887498949f
#define REVF 2.44140625e-4f          // 1/4096 (exact) — LUT step in revolutions
#define INV2PI 0.15915494309189535f  // 1/(2*pi): radians -> revolutions
#define EXPC 0.1275174394255169f     // log2(e) / sqrt(2*dh)

// workspace layout, in floats
#define OFF_P     0          // P[NC][NB][NH][ND] f32 = 8388608 floats (33.5 MB)
#define OFF_ZPART 8388608    // [NC][NB][NH] = 8192
#define OFF_INVZ  8396800    // [NB*NH] = 256

// 16-lane-group sum via DPP row_shr (pure VALU); lane 16k+15 holds the sum.
__device__ __forceinline__ float dpp_reduce16(float p) {
    int y;
    y = __builtin_amdgcn_update_dpp(0, __float_as_int(p), 0x111, 0xF, 0xF, true);
    p += __int_as_float(y);
    y = __builtin_amdgcn_update_dpp(0, __float_as_int(p), 0x112, 0xF, 0xF, true);
    p += __int_as_float(y);
    y = __builtin_amdgcn_update_dpp(0, __float_as_int(p), 0x114, 0xF, 0xF, true);
    p += __int_as_float(y);
    y = __builtin_amdgcn_update_dpp(0, __float_as_int(p), 0x118, 0xF, 0xF, true);
    p += __int_as_float(y);
    return p;
}

#if __has_builtin(__builtin_amdgcn_exp2f)
#define EXP2F(x) __builtin_amdgcn_exp2f(x)
#else
#define EXP2F(x) exp2f(x)
#endif

// Packed FP32 FMA (VOP3P). src1 low/high half broadcast via op_sel.
#define PKFMA_LO(acc, e2, v2) \
    asm("v_pk_fma_f32 %0, %1, %2, %0 op_sel:[0,0,0] op_sel_hi:[1,0,1]" \
        : "+v"(acc) : "v"(e2), "v"(v2))
#define PKFMA_HI(acc, e2, v2) \
    asm("v_pk_fma_f32 %0, %1, %2, %0 op_sel:[0,1,0] op_sel_hi:[1,1,1]" \
        : "+v"(acc) : "v"(e2), "v"(v2))

// Fused scores + unnormalized per-head context, one pass over cached.
// R23: R13's ping-pong schedule (loads issue right after a barrier, hide
// under ACC, are consumed by the NEXT score — never crossing a barrier),
// now correctly provisioned: __launch_bounds__(256,2) caps VGPR at 256
// (vA+vB+acc2+params ~160 fits; R13's (256,1) allowed >256-class alloc and
// dropped to 1 block/CU), plus the R18 slim score (1 fma + 1 v_cos/elem).
// Mechanism targeted: a wave in its VALU phase issues no memory ops; at 2
// waves/SIMD this leaves the memory pipe idle ~40% of time. Bounding the
// gap between load bursts to one phase (~1.3K cyc) restores BW overlap.
__global__ __launch_bounds__(256, 2) void k_fused(const float* __restrict__ cached,
                                                  const float* __restrict__ x,
                                                  const float* __restrict__ t,
                                                  const float* __restrict__ wq,
                                                  const float* __restrict__ bq,
                                                  const float* __restrict__ wk,
                                                  const float* __restrict__ bk,
                                                  float* __restrict__ ws) {
    __shared__ float se[2][RG][16];    // e broadcast, double-buffered (1 KB)
    int tid = threadIdx.x;
    int b = blockIdx.x >> 5;           // / NC
    int c = blockIdx.x & (NC - 1);
    int s0 = c * SC;
    int m = tid * 4;

    // per-column constants: arg_rev = v * krR + kdR  (revolutions)
    float4 wkv = *(const float4*)(wk + m);
    float4 kbv = *(const float4*)(bk + m);
    float4 krR;
    krR.x = INV2PI / (1.0f + fabsf(wkv.x));
    krR.y = INV2PI / (1.0f + fabsf(wkv.y));
    krR.z = INV2PI / (1.0f + fabsf(wkv.z));
    krR.w = INV2PI / (1.0f + fabsf(wkv.w));

    float tphi = t[b] * PHIF;
    float4 xv = *(const float4*)(x + b * ND + m);
    float4 wqv = *(const float4*)(wq + m);
    float4 bqv = *(const float4*)(bq + m);
    float4 kdR;   // bk/(2pi) - rint(theta_q*KF)*REVF  (query stays quantized)
    kdR.x = kbv.x * INV2PI - rintf((xv.x / (1.0f + fabsf(wqv.x)) + bqv.x + tphi) * KF) * REVF;
    kdR.y = kbv.y * INV2PI - rintf((xv.y / (1.0f + fabsf(wqv.y)) + bqv.y + tphi) * KF) * REVF;
    kdR.z = kbv.z * INV2PI - rintf((xv.z / (1.0f + fabsf(wqv.z)) + bqv.z + tphi) * KF) * REVF;
    kdR.w = kbv.w * INV2PI - rintf((xv.w / (1.0f + fabsf(wqv.w)) + bqv.w + tphi) * KF) * REVF;

    // acc2[p][q] = (ctxh[2p][col q], ctxh[2p+1][col q]) — 64 VGPRs
    float2 acc2[8][4];
    #pragma unroll
    for (int p = 0; p < 8; ++p)
        #pragma unroll
        for (int q = 0; q < 4; ++q) acc2[p][q] = make_float2(0.f, 0.f);
    float zacc = 0.f;

    const float* base = cached + ((size_t)b * NS + s0) * ND + m;
    float4 vA[RG], vB[RG];

#define LOADG(dst, g) { \
    const float* bp = base + (size_t)(g) * (RG * ND); \
    _Pragma("unroll") \
    for (int r = 0; r < RG; ++r) dst[r] = *(const float4*)(bp + (size_t)r * ND); }

    // slim score: one fma + one v_cos per element (v_cos takes revolutions)
#define SCOREG(v, buf) { \
    _Pragma("unroll") \
    for (int r = 0; r < RG; ++r) { \
        float c0 = __builtin_amdgcn_cosf(fmaf(v[r].x, krR.x, kdR.x)); \
        float c1 = __builtin_amdgcn_cosf(fmaf(v[r].y, krR.y, kdR.y)); \
        float c2 = __builtin_amdgcn_cosf(fmaf(v[r].z, krR.z, kdR.z)); \
        float c3 = __builtin_amdgcn_cosf(fmaf(v[r].w, krR.w, kdR.w)); \
        float p = (c0 + c1) + (c2 + c3); \
        p = dpp_reduce16(p); \
        float e = EXP2F(p * EXPC);   /* |score| <= 5.66, no max pass */ \
        zacc += e;                   /* valid in lanes 15 mod 16 */ \
        if ((tid & 15) == 15) se[buf][r][tid >> 4] = e; \
    } }

#define ACC4P(v, buf) { \
    _Pragma("unroll") \
    for (int r = 0; r < RG; ++r) { \
        const float2* s2 = (const float2*)se[buf][r]; \
        float2 vxy = make_float2(v[r].x, v[r].y); \
        float2 vzw = make_float2(v[r].z, v[r].w); \
        _Pragma("unroll") \
        for (int p = 0; p < 8; ++p) { \
            float2 e2 = s2[p]; \
            PKFMA_LO(acc2[p][0], e2, vxy); \
            PKFMA_HI(acc2[p][1], e2, vxy); \
            PKFMA_LO(acc2[p][2], e2, vzw); \
            PKFMA_HI(acc2[p][3], e2, vzw); \
        } \
    } }

    LOADG(vA, 0)
    SCOREG(vA, 0)                          // first group: latency exposed once
    for (int gp = 0; gp < NG / 2; ++gp) {
        __syncthreads();                   // se[0] visible; no loads in flight
        LOADG(vB, gp * 2 + 1)              // burst issues here; hides under ACC
        ACC4P(vA, 0)
        SCOREG(vB, 1)                      // consumes vB before next barrier
        __syncthreads();                   // se[1] visible; no loads in flight
        if (gp < NG / 2 - 1) {
            LOADG(vA, gp * 2 + 2)          // burst; hides under ACC(vB)
        }
        ACC4P(vB, 1)
        if (gp < NG / 2 - 1) {
            SCOREG(vA, 0)
        }
    }
#undef ACC4P
#undef SCOREG
#undef LOADG

    // write per-head context partials, coalesced per h
    float* P = ws + OFF_P + (size_t)(c * NB + b) * (NH * ND) + m;
    #pragma unroll
    for (int p = 0; p < 8; ++p) {
        float4 lo = make_float4(acc2[p][0].x, acc2[p][1].x, acc2[p][2].x, acc2[p][3].x);
        float4 hi = make_float4(acc2[p][0].y, acc2[p][1].y, acc2[p][2].y, acc2[p][3].y);
        *(float4*)(P + (2 * p) * ND) = lo;
        *(float4*)(P + (2 * p + 1) * ND) = hi;
    }
    if ((tid & 15) == 15)
        ws[OFF_ZPART + (c * NB + b) * NH + (tid >> 4)] = zacc;
}

__global__ __launch_bounds__(256) void k_z(float* __restrict__ ws) {
    int i = threadIdx.x;   // b*NH + h
    float s = 0.f;
    #pragma unroll
    for (int c = 0; c < NC; ++c) s += ws[OFF_ZPART + c * 256 + i];
    ws[OFF_INVZ + i] = 1.0f / s;
}

__global__ __launch_bounds__(256) void k_out(const float* __restrict__ t,
                                             const float* __restrict__ wo,
                                             const float* __restrict__ bo,
                                             const float* __restrict__ osc,
                                             const float* __restrict__ ws,
                                             float* __restrict__ out) {
    __shared__ float red[4][64];
    int bid = blockIdx.x;          // NB*16 = 256
    int b = bid >> 4, mc = bid & 15;
    int tid = threadIdx.x;
    int cq = tid >> 6, ml = tid & 63;
    int m = mc * 64 + ml;
    const float* P = ws + OFF_P;
    float ctx = 0.f;
    #pragma unroll
    for (int h = 0; h < NH; ++h) {
        float s = 0.f;
        #pragma unroll
        for (int i = 0; i < NC / 4; ++i) {
            int c = cq * (NC / 4) + i;
            s += P[(size_t)(c * NB + b) * (NH * ND) + h * ND + m];
        }
        ctx = fmaf(s, ws[OFF_INVZ + b * NH + h], ctx);
    }
    red[cq][ml] = ctx;
    __syncthreads();
    if (cq == 0) {
        ctx = ((red[0][ml] + red[1][ml]) + (red[2][ml] + red[3][ml]));
        float theta = ctx / (1.0f + fabsf(wo[m])) + bo[m] + t[b] * PHIF;
        int idx = ((int)rintf(theta * KF)) & (LUTN - 1);
        float ang = (float)idx * (2.0f * 3.14159265358979323846f / LUTN);
        // precise libm trig: bit-matches the np table entries
        out[b * ND + m] = osc[m] * (cosf(ang) + sinf(ang));
    }
}

extern "C" void kernel_launch(void* const* d_in, const int* in_sizes, int n_in,
                              void* d_out, int out_size, void* d_ws, size_t ws_size,
                              hipStream_t stream) {
    const float* x      = (const float*)d_in[0];
    const float* cached = (const float*)d_in[1];
    const float* t      = (const float*)d_in[2];
    const float* wq     = (const float*)d_in[3];
    const float* bq     = (const float*)d_in[4];
    const float* wk     = (const float*)d_in[5];
    const float* bk     = (const float*)d_in[6];
    const float* wo     = (const float*)d_in[7];
    const float* bo     = (const float*)d_in[8];
    const float* osc    = (const float*)d_in[9];
    float* ws  = (float*)d_ws;
    float* out = (float*)d_out;

    k_fused<<<NB * NC, 256, 0, stream>>>(cached, x, t, wq, bq, wk, bk, ws);
    k_z<<<1, 256, 0, stream>>>(ws);
    k_out<<<NB * (ND / 64), 256, 0, stream>>>(t, wo, bo, osc, ws, out);
}